// Round 13
// baseline (16072.089 us; speedup 1.0000x reference)
//
#include <hip/hip_runtime.h>
#include <hip/hip_bf16.h>
#include <math.h>

// ---------------------------------------------------------------------------
// SpatialTransformerEncoder — round 13: MFMA + ws weights on a 256-thread
// skeleton. 1024-thread workgroups are pinned at 64 VGPRs by the compiler
// (r8-r12, spills); 256-thread + __launch_bounds__(256,1) proved 136 VGPRs
// (r7). 4 waves/block, each wave owns 4x the N-tiles. FC2 partial sums are
// accumulated into X per chunk (no persistent cross-chunk accumulators).
// ---------------------------------------------------------------------------

#define NB   2048
#define NC   3
#define NN   32
#define NE   256
#define NH   8
#define HDIM 32
#define NL   3
#define NMLP 1024
#define NP   256
#define NK   17
#define NS   (NB*NC)
#define NT   256       // threads per block (4 waves)
#define NW   4         // waves per block
#define AST  264

// ws layout (u16 offsets): hi block then lo block; [qkv][ap][fc1][fc2][kv],
// each [l][n][k] k-fastest (K=256 except fc2 K=1024).
#define SZ_QKV  589824
#define SZ_AP   196608
#define SZ_FC1  786432
#define SZ_FC2  786432
#define SZ_KV   131072
#define OFF_QKV 0
#define OFF_AP  (OFF_QKV + SZ_QKV)
#define OFF_FC1 (OFF_AP + SZ_AP)
#define OFF_FC2 (OFF_FC1 + SZ_FC1)
#define OFF_KV  (OFF_FC2 + SZ_FC2)
#define WTOT    (OFF_KV + SZ_KV)            // 2490368 u16 per polarity
#define WS_NEEDED ((size_t)WTOT * 2 * 2)

typedef unsigned short u16;
typedef __attribute__((ext_vector_type(8))) short short8;
typedef __attribute__((ext_vector_type(4))) float float4v;

struct Params {
  const void* x; const void* mask;
  const void* kp_w; const void* kp_b;
  const void* view_tokens; const void* view_pos;
  const void* ln1_s; const void* ln1_b;
  const void* qkv_w; const void* qkv_b;
  const void* ap_w; const void* ap_b;
  const void* ln2_s; const void* ln2_b;
  const void* fc1_w; const void* fc1_b;
  const void* fc2_w; const void* fc2_b;
  const void* pool_probe;
  const void* pool_ln1_s; const void* pool_ln1_b;
  const void* pool_q_w; const void* pool_q_b;
  const void* pool_kv_w; const void* pool_kv_b;
  const void* pool_ap_w; const void* pool_ap_b;
  const void* pool_ln2_s; const void* pool_ln2_b;
  const void* pool_fc1_w; const void* pool_fc1_b;
  const void* pool_fc2_w; const void* pool_fc2_b;
  const void* pool_out_w; const void* pool_out_b;
  const void* last_s; const void* last_b;
  float* out;
  u16* ws;
};

__device__ __forceinline__ float b2f(u16 u) {
  return __uint_as_float(((unsigned)u) << 16);
}
__device__ __forceinline__ u16 cvt16(float v) {
  return __bfloat16_as_ushort(__float2bfloat16(v));
}
__device__ __forceinline__ float geluf(float v) {
  return 0.5f * v * (1.0f + erff(v * 0.70710678118654752f));
}
template <bool BF>
__device__ __forceinline__ float LD(const void* q, int i) {
  if constexpr (BF) return b2f(((const u16*)q)[i]);
  else return ((const float*)q)[i];
}
__device__ __forceinline__ float4v vzero() {
  float4v z; z[0] = 0.f; z[1] = 0.f; z[2] = 0.f; z[3] = 0.f; return z;
}

// ---------------- prep: W[k][n] (fp32/bf16) -> ws hi/lo [n][k] ----------------
template <bool BF>
__device__ void prep_body(const Params& p, int idx) {
  size_t i = idx, src; const void* W;
  if (i < SZ_QKV) {
    const size_t l = i / 196608, r = i % 196608, n = r / 256, k = r % 256;
    W = p.qkv_w; src = l * 196608 + k * 768 + n;
  } else if ((i -= SZ_QKV) < SZ_AP) {
    const size_t l = i / 65536, r = i % 65536, n = r / 256, k = r % 256;
    W = p.ap_w; src = l * 65536 + k * 256 + n;
  } else if ((i -= SZ_AP) < SZ_FC1) {
    const size_t l = i / 262144, r = i % 262144, n = r / 256, k = r % 256;
    W = p.fc1_w; src = l * 262144 + k * 1024 + n;
  } else if ((i -= SZ_FC1) < SZ_FC2) {
    const size_t l = i / 262144, r = i % 262144, n = r / 1024, k = r % 1024;
    W = p.fc2_w; src = l * 262144 + k * 256 + n;
  } else {
    i -= SZ_FC2;
    const size_t n = i / 256, k = i % 256;
    W = p.pool_kv_w; src = k * 512 + n;
  }
  u16 hi, lo;
  if constexpr (BF) {
    hi = ((const u16*)W)[src]; lo = 0;
  } else {
    const float wv = ((const float*)W)[src];
    hi = cvt16(wv);
    lo = cvt16(wv - b2f(hi));
  }
  p.ws[idx] = hi;
  p.ws[WTOT + idx] = lo;
}

__global__ __launch_bounds__(256)
void prep_kernel(Params p) {
  const int idx = blockIdx.x * 256 + threadIdx.x;
  if (idx >= WTOT) return;
  const bool isbf = (((const u16*)p.ln1_s)[0] == 0x3F80);
  if (isbf) prep_body<true>(p, idx);
  else      prep_body<false>(p, idx);
}

struct alignas(16) Smem {
  float X[NK][NE];
  float U[NK][768];
  float Q[NE];
  float O[NE];
  float RowA[NE];
  float Hh[NMLP];
  float Pp[NH][NK];
  float Red[NW];
  u16 Ahi[32 * AST];
  u16 Alo[32 * AST];
  u16 Hhi[32 * AST];
  u16 Hlo[32 * AST];
  int Idx[NK];
};

// ---- LayerNorm over 17 rows -> hi/lo bf16 A-buffers (4 waves) ----
template <bool BF>
__device__ __forceinline__ void ln_hl(const float* __restrict__ In,
                                      u16* __restrict__ Oh, u16* __restrict__ Ol,
                                      const void* __restrict__ gam,
                                      const void* __restrict__ bet) {
  const int lane = threadIdx.x & 63, w = threadIdx.x >> 6;
  for (int t = w; t < NK; t += NW) {
    const float* row = In + t * NE;
    float sum = 0.f, sq = 0.f;
#pragma unroll
    for (int kk = 0; kk < NE / 64; ++kk) {
      const float v = row[lane + 64 * kk];
      sum += v; sq += v * v;
    }
#pragma unroll
    for (int off = 32; off > 0; off >>= 1) {
      sum += __shfl_down(sum, off, 64);
      sq  += __shfl_down(sq,  off, 64);
    }
    sum = __shfl(sum, 0, 64);
    sq  = __shfl(sq,  0, 64);
    const float mu = sum * (1.0f / NE);
    const float r  = rsqrtf(sq * (1.0f / NE) - mu * mu + 1e-5f);
#pragma unroll
    for (int kk = 0; kk < NE / 64; ++kk) {
      const int k = lane + 64 * kk;
      const float v = (row[k] - mu) * r * LD<BF>(gam, k) + LD<BF>(bet, k);
      const u16 hv = cvt16(v);
      Oh[t * AST + k] = hv;
      Ol[t * AST + k] = cvt16(v - b2f(hv));
    }
  }
}

// ---- MFMA tile (WS): B pre-transposed bf16 hi/lo, one short8 per fragment ----
template <bool BF>
__device__ __forceinline__ void mfma_ws(const u16* __restrict__ Ah,
                                        const u16* __restrict__ Al,
                                        const u16* __restrict__ Wh,
                                        const u16* __restrict__ Wl,
                                        const int kst, const int koff,
                                        const int n,
                                        float4v& D0, float4v& D1) {
  const int lane = threadIdx.x & 63;
  const int col = lane & 15, quad = lane >> 4;
  const u16* __restrict__ brh = Wh + (size_t)n * kst + koff;
  const u16* __restrict__ brl = Wl + (size_t)n * kst + koff;
  for (int ks = 0; ks < 8; ++ks) {
    const int k0 = ks * 32 + quad * 8;
    const short8 ah0 = *(const short8*)(Ah + col * AST + k0);
    const short8 ah1 = *(const short8*)(Ah + (16 + col) * AST + k0);
    const short8 bh  = *(const short8*)(brh + k0);
    D0 = __builtin_amdgcn_mfma_f32_16x16x32_bf16(ah0, bh, D0, 0, 0, 0);
    D1 = __builtin_amdgcn_mfma_f32_16x16x32_bf16(ah1, bh, D1, 0, 0, 0);
    {
      const short8 al0 = *(const short8*)(Al + col * AST + k0);
      const short8 al1 = *(const short8*)(Al + (16 + col) * AST + k0);
      D0 = __builtin_amdgcn_mfma_f32_16x16x32_bf16(al0, bh, D0, 0, 0, 0);
      D1 = __builtin_amdgcn_mfma_f32_16x16x32_bf16(al1, bh, D1, 0, 0, 0);
    }
    if constexpr (!BF) {
      const short8 bl = *(const short8*)(brl + k0);
      D0 = __builtin_amdgcn_mfma_f32_16x16x32_bf16(ah0, bl, D0, 0, 0, 0);
      D1 = __builtin_amdgcn_mfma_f32_16x16x32_bf16(ah1, bl, D1, 0, 0, 0);
    }
  }
}

// ---- MFMA tile, inline fallback (W fp32/bf16 row-major global) ----
template <bool BF>
__device__ __forceinline__ void mfma_in(const u16* __restrict__ Ah,
                                        const u16* __restrict__ Al,
                                        const void* __restrict__ W, const int wN,
                                        const int n,
                                        float4v& D0, float4v& D1) {
  const int lane = threadIdx.x & 63;
  const int col = lane & 15, quad = lane >> 4;
  for (int ks = 0; ks < 8; ++ks) {
    const int k0 = ks * 32 + quad * 8;
    const short8 ah0 = *(const short8*)(Ah + col * AST + k0);
    const short8 ah1 = *(const short8*)(Ah + (16 + col) * AST + k0);
    short8 bh, bl;
#pragma unroll
    for (int j2 = 0; j2 < 8; ++j2) {
      const size_t off = (size_t)(k0 + j2) * wN + n;
      if constexpr (BF) {
        bh[j2] = (short)((const u16*)W)[off];
      } else {
        const float wv = ((const float*)W)[off];
        const u16 hv = cvt16(wv);
        bh[j2] = (short)hv;
        bl[j2] = (short)cvt16(wv - b2f(hv));
      }
    }
    D0 = __builtin_amdgcn_mfma_f32_16x16x32_bf16(ah0, bh, D0, 0, 0, 0);
    D1 = __builtin_amdgcn_mfma_f32_16x16x32_bf16(ah1, bh, D1, 0, 0, 0);
    {
      const short8 al0 = *(const short8*)(Al + col * AST + k0);
      const short8 al1 = *(const short8*)(Al + (16 + col) * AST + k0);
      D0 = __builtin_amdgcn_mfma_f32_16x16x32_bf16(al0, bh, D0, 0, 0, 0);
      D1 = __builtin_amdgcn_mfma_f32_16x16x32_bf16(al1, bh, D1, 0, 0, 0);
    }
    if constexpr (!BF) {
      D0 = __builtin_amdgcn_mfma_f32_16x16x32_bf16(ah0, bl, D0, 0, 0, 0);
      D1 = __builtin_amdgcn_mfma_f32_16x16x32_bf16(ah1, bl, D1, 0, 0, 0);
    }
  }
}

__device__ __forceinline__ float block_sum(float v, float* sRed) {
#pragma unroll
  for (int off = 32; off > 0; off >>= 1) v += __shfl_down(v, off, 64);
  __syncthreads();
  if ((threadIdx.x & 63) == 0) sRed[threadIdx.x >> 6] = v;
  __syncthreads();
  return sRed[0] + sRed[1] + sRed[2] + sRed[3];
}

template <bool BF, bool WS>
__device__ void body(const Params& p, Smem& sm) {
  const int s   = blockIdx.x;
  const int c   = s % NC;
  const int tid = threadIdx.x;
  const size_t EB = BF ? 2 : 4;
  const int lane = tid & 63, wv_ = tid >> 6, col = lane & 15, quad = lane >> 4;
  const u16* wsh = p.ws;
  const u16* wsl = p.ws + WTOT;

  for (int i = tid; i < 32 * AST; i += NT) {
    sm.Ahi[i] = 0; sm.Alo[i] = 0; sm.Hhi[i] = 0; sm.Hlo[i] = 0;
  }

  if (tid == 0) {
    const unsigned int* mw = (const unsigned int*)p.mask;
    bool byte_layout = false;
    for (int i = 0; i < 8; ++i) {
      const unsigned int w = mw[i];
      if (w != 0u && w != 1u && w != 0x3F800000u) { byte_layout = true; break; }
    }
    int np_ = 0;
    sm.Idx[np_++] = -1;
    if (byte_layout) {
      const unsigned char* mb = (const unsigned char*)p.mask;
      for (int n = 0; n < NN && np_ < NK; ++n)
        if (mb[(size_t)s * NN + n]) sm.Idx[np_++] = n;
    } else {
      for (int n = 0; n < NN && np_ < NK; ++n)
        if (mw[(size_t)s * NN + n] != 0u) sm.Idx[np_++] = n;
    }
    while (np_ < NK) sm.Idx[np_++] = 0;
  }
  __syncthreads();

  // embedding (r7 pattern: thread e = tid, loop all t)
  {
    const int e = tid;
    const float kw0 = LD<BF>(p.kp_w, e);
    const float kw1 = LD<BF>(p.kp_w, NE + e);
    const float kb  = LD<BF>(p.kp_b, e);
    const int   i2  = e & ~1;
    const float freq = expf(-((float)i2 / (float)NE) * logf(10000.0f));
    const float vt = LD<BF>(p.view_tokens, c * NE + e) + LD<BF>(p.view_pos, c * NE + e);
    for (int t = 0; t < NK; ++t) {
      const int n = sm.Idx[t];
      float v;
      if (n < 0) {
        v = vt;
      } else {
        const float x0 = LD<BF>(p.x, (s * NN + n) * 2 + 0);
        const float x1 = LD<BF>(p.x, (s * NN + n) * 2 + 1);
        const float ang = (float)n * freq;
        const float pe  = (e & 1) ? cosf(ang) : sinf(ang);
        v = x0 * kw0 + x1 * kw1 + kb + pe;
      }
      sm.X[t][e] = v;
    }
  }
  __syncthreads();

  for (int l = 0; l < NL; ++l) {
    const void* qkvw = (const char*)p.qkv_w + (size_t)l * NE * 3 * NE * EB;
    const void* qkvb = (const char*)p.qkv_b + (size_t)l * 3 * NE * EB;
    const void* apw  = (const char*)p.ap_w  + (size_t)l * NE * NE * EB;
    const void* apb  = (const char*)p.ap_b  + (size_t)l * NE * EB;
    const void* f1b  = (const char*)p.fc1_b + (size_t)l * NMLP * EB;
    const void* f2bb = (const char*)p.fc2_b + (size_t)l * NE * EB;

    ln_hl<BF>(&sm.X[0][0], sm.Ahi, sm.Alo,
              (const char*)p.ln1_s + (size_t)l * NE * EB,
              (const char*)p.ln1_b + (size_t)l * NE * EB);
    __syncthreads();

    // QKV: 48 N-tiles, 12 per wave
    for (int jj = 0; jj < 12; ++jj) {
      const int n = (wv_ + jj * NW) * 16 + col;
      float4v D0 = vzero(), D1 = vzero();
      if constexpr (WS)
        mfma_ws<BF>(sm.Ahi, sm.Alo, wsh + OFF_QKV + (size_t)l * 196608,
                    wsl + OFF_QKV + (size_t)l * 196608, 256, 0, n, D0, D1);
      else
        mfma_in<BF>(sm.Ahi, sm.Alo, qkvw, 3 * NE, n, D0, D1);
      const float bb = LD<BF>(qkvb, n);
#pragma unroll
      for (int r = 0; r < 4; ++r) {
        const int m0 = quad * 4 + r;
        if (m0 < NK) sm.U[m0][n] = D0[r] + bb;
        const int m1 = 16 + quad * 4 + r;
        if (m1 < NK) sm.U[m1][n] = D1[r] + bb;
      }
    }
    __syncthreads();

    // attention (VALU)
    if (tid < NH * NK) {
      const int h = tid / NK, t = tid % NK;
      const float* qr = &sm.U[t][h * HDIM];
      float sc[NK];
      float mx = -1e30f;
#pragma unroll
      for (int u = 0; u < NK; ++u) {
        const float* kr = &sm.U[u][NE + h * HDIM];
        float d = 0.f;
        for (int i = 0; i < HDIM; ++i) d += qr[i] * kr[i];
        d *= 0.17677669529663687f;
        sc[u] = d;
        mx = fmaxf(mx, d);
      }
      float den = 0.f;
#pragma unroll
      for (int u = 0; u < NK; ++u) { sc[u] = __expf(sc[u] - mx); den += sc[u]; }
      const float inv = 1.0f / den;
      for (int i = 0; i < HDIM; ++i) {
        float o = 0.f;
#pragma unroll
        for (int u = 0; u < NK; ++u) o += sc[u] * sm.U[u][2 * NE + h * HDIM + i];
        o *= inv;
        const int jc = h * HDIM + i;
        const u16 hv = cvt16(o);
        sm.Ahi[t * AST + jc] = hv;
        sm.Alo[t * AST + jc] = cvt16(o - b2f(hv));
      }
    }
    __syncthreads();

    // proj + residual: 16 tiles, 4 per wave
    for (int jj = 0; jj < 4; ++jj) {
      const int n = (wv_ + jj * NW) * 16 + col;
      float4v D0 = vzero(), D1 = vzero();
      if constexpr (WS)
        mfma_ws<BF>(sm.Ahi, sm.Alo, wsh + OFF_AP + (size_t)l * 65536,
                    wsl + OFF_AP + (size_t)l * 65536, 256, 0, n, D0, D1);
      else
        mfma_in<BF>(sm.Ahi, sm.Alo, apw, NE, n, D0, D1);
      const float bb = LD<BF>(apb, n);
#pragma unroll
      for (int r = 0; r < 4; ++r) {
        const int m0 = quad * 4 + r;
        if (m0 < NK) sm.X[m0][n] = sm.X[m0][n] + D0[r] + bb;
        const int m1 = 16 + quad * 4 + r;
        if (m1 < NK) sm.X[m1][n] = sm.X[m1][n] + D1[r] + bb;
      }
    }
    __syncthreads();

    ln_hl<BF>(&sm.X[0][0], sm.Ahi, sm.Alo,
              (const char*)p.ln2_s + (size_t)l * NE * EB,
              (const char*)p.ln2_b + (size_t)l * NE * EB);
    __syncthreads();

    // FC1 (+GELU) chunk -> H; FC2 chunk partial added into X (bias at chunk 0)
    for (int chunk = 0; chunk < 4; ++chunk) {
      for (int jj = 0; jj < 4; ++jj) {
        const int n = (wv_ + jj * NW) * 16 + col;
        float4v D0 = vzero(), D1 = vzero();
        if constexpr (WS)
          mfma_ws<BF>(sm.Ahi, sm.Alo,
                      wsh + OFF_FC1 + (size_t)l * 262144 + (size_t)chunk * 65536,
                      wsl + OFF_FC1 + (size_t)l * 262144 + (size_t)chunk * 65536,
                      256, 0, n, D0, D1);
        else {
          const void* f1w = (const char*)p.fc1_w +
              ((size_t)l * NE * NMLP + (size_t)chunk * 256) * EB;
          mfma_in<BF>(sm.Ahi, sm.Alo, f1w, NMLP, n, D0, D1);
        }
        const float bb = LD<BF>(f1b, chunk * 256 + n);
#pragma unroll
        for (int r = 0; r < 4; ++r) {
          const int m0 = quad * 4 + r;
          if (m0 < NK) {
            const float v = geluf(D0[r] + bb);
            const u16 hv = cvt16(v);
            sm.Hhi[m0 * AST + n] = hv;
            sm.Hlo[m0 * AST + n] = cvt16(v - b2f(hv));
          }
          const int m1 = 16 + quad * 4 + r;
          if (m1 < NK) {
            const float v = geluf(D1[r] + bb);
            const u16 hv = cvt16(v);
            sm.Hhi[m1 * AST + n] = hv;
            sm.Hlo[m1 * AST + n] = cvt16(v - b2f(hv));
          }
        }
      }
      __syncthreads();
      for (int jj = 0; jj < 4; ++jj) {
        const int n = (wv_ + jj * NW) * 16 + col;
        float4v D0 = vzero(), D1 = vzero();
        if constexpr (WS)
          mfma_ws<BF>(sm.Hhi, sm.Hlo, wsh + OFF_FC2 + (size_t)l * 262144,
                      wsl + OFF_FC2 + (size_t)l * 262144,
                      1024, chunk * 256, n, D0, D1);
        else {
          const void* f2w = (const char*)p.fc2_w +
              ((size_t)l * NMLP * NE + (size_t)chunk * 256 * NE) * EB;
          mfma_in<BF>(sm.Hhi, sm.Hlo, f2w, NE, n, D0, D1);
        }
        const float bb = (chunk == 0) ? LD<BF>(f2bb, n) : 0.f;
#pragma unroll
        for (int r = 0; r < 4; ++r) {
          const int m0 = quad * 4 + r;
          if (m0 < NK) sm.X[m0][n] = sm.X[m0][n] + D0[r] + bb;
          const int m1 = 16 + quad * 4 + r;
          if (m1 < NK) sm.X[m1][n] = sm.X[m1][n] + D1[r] + bb;
        }
      }
      __syncthreads();
    }
  }

  // ---- attention pooling ----
  ln_hl<BF>(&sm.X[0][0], sm.Ahi, sm.Alo, p.pool_ln1_s, p.pool_ln1_b);
  __syncthreads();
  {
    const int j = tid;
    float a = LD<BF>(p.pool_q_b, j);
    for (int k = 0; k < NE; k += 4) {
      a += LD<BF>(p.pool_probe, k + 0) * LD<BF>(p.pool_q_w, (k + 0) * NE + j) +
           LD<BF>(p.pool_probe, k + 1) * LD<BF>(p.pool_q_w, (k + 1) * NE + j) +
           LD<BF>(p.pool_probe, k + 2) * LD<BF>(p.pool_q_w, (k + 2) * NE + j) +
           LD<BF>(p.pool_probe, k + 3) * LD<BF>(p.pool_q_w, (k + 3) * NE + j);
    }
    sm.Q[j] = a;
  }
  // pool KV: 32 tiles, 8 per wave
  for (int jj = 0; jj < 8; ++jj) {
    const int n = (wv_ + jj * NW) * 16 + col;
    float4v D0 = vzero(), D1 = vzero();
    if constexpr (WS)
      mfma_ws<BF>(sm.Ahi, sm.Alo, wsh + OFF_KV, wsl + OFF_KV, 256, 0, n, D0, D1);
    else
      mfma_in<BF>(sm.Ahi, sm.Alo, p.pool_kv_w, 2 * NE, n, D0, D1);
    const float bb = LD<BF>(p.pool_kv_b, n);
#pragma unroll
    for (int r = 0; r < 4; ++r) {
      const int m0 = quad * 4 + r;
      if (m0 < NK) sm.U[m0][n] = D0[r] + bb;
      const int m1 = 16 + quad * 4 + r;
      if (m1 < NK) sm.U[m1][n] = D1[r] + bb;
    }
  }
  __syncthreads();
  if (tid < NH) {
    const int h = tid;
    float sc[NK];
    float mx = -1e30f;
#pragma unroll
    for (int u = 0; u < NK; ++u) {
      float d = 0.f;
      for (int i = 0; i < HDIM; ++i) d += sm.Q[h * HDIM + i] * sm.U[u][h * HDIM + i];
      d *= 0.17677669529663687f;
      sc[u] = d;
      mx = fmaxf(mx, d);
    }
    float den = 0.f;
#pragma unroll
    for (int u = 0; u < NK; ++u) { sc[u] = __expf(sc[u] - mx); den += sc[u]; }
    const float inv = 1.0f / den;
#pragma unroll
    for (int u = 0; u < NK; ++u) sm.Pp[h][u] = sc[u] * inv;
  }
  __syncthreads();
  {
    const int j = tid, h = j >> 5, i = j & 31;
    float o = 0.f;
#pragma unroll
    for (int u = 0; u < NK; ++u) o += sm.Pp[h][u] * sm.U[u][NE + h * HDIM + i];
    sm.O[j] = o;
  }
  __syncthreads();
  float yv;
  {
    const int j = tid;
    float a = LD<BF>(p.pool_ap_b, j);
    for (int k = 0; k < NE; k += 4) {
      const float4 oo = *(const float4*)&sm.O[k];
      a += oo.x * LD<BF>(p.pool_ap_w, (k + 0) * NE + j) +
           oo.y * LD<BF>(p.pool_ap_w, (k + 1) * NE + j) +
           oo.z * LD<BF>(p.pool_ap_w, (k + 2) * NE + j) +
           oo.w * LD<BF>(p.pool_ap_w, (k + 3) * NE + j);
    }
    yv = LD<BF>(p.pool_probe, j) + a;
  }
  {
    const float s1 = block_sum(yv, sm.Red);
    const float s2 = block_sum(yv * yv, sm.Red);
    const float mu = s1 * (1.0f / NE);
    const float r  = rsqrtf(s2 * (1.0f / NE) - mu * mu + 1e-5f);
    sm.Q[tid] = (yv - mu) * r * LD<BF>(p.pool_ln2_s, tid) + LD<BF>(p.pool_ln2_b, tid);
  }
  __syncthreads();
  // pool MLP hidden: 4 cols per thread (r7 pattern)
  {
    const int j = tid;
    float h1[4];
#pragma unroll
    for (int c4 = 0; c4 < 4; ++c4) h1[c4] = LD<BF>(p.pool_fc1_b, c4 * NE + j);
    for (int k = 0; k < NE; k += 4) {
      const float4 nq = *(const float4*)&sm.Q[k];
#pragma unroll
      for (int c4 = 0; c4 < 4; ++c4) {
        const int cjj = c4 * NE + j;
        h1[c4] += nq.x * LD<BF>(p.pool_fc1_w, (k + 0) * NMLP + cjj) +
                  nq.y * LD<BF>(p.pool_fc1_w, (k + 1) * NMLP + cjj) +
                  nq.z * LD<BF>(p.pool_fc1_w, (k + 2) * NMLP + cjj) +
                  nq.w * LD<BF>(p.pool_fc1_w, (k + 3) * NMLP + cjj);
      }
    }
#pragma unroll
    for (int c4 = 0; c4 < 4; ++c4) sm.Hh[c4 * NE + j] = geluf(h1[c4]);
  }
  __syncthreads();
  {
    const int j = tid;
    float a = LD<BF>(p.pool_fc2_b, j);
    for (int k = 0; k < NMLP; k += 4) {
      const float4 hh = *(const float4*)&sm.Hh[k];
      a += hh.x * LD<BF>(p.pool_fc2_w, (k + 0) * NE + j) +
           hh.y * LD<BF>(p.pool_fc2_w, (k + 1) * NE + j) +
           hh.z * LD<BF>(p.pool_fc2_w, (k + 2) * NE + j) +
           hh.w * LD<BF>(p.pool_fc2_w, (k + 3) * NE + j);
    }
    yv += a;
    sm.RowA[j] = yv;
  }
  __syncthreads();
  float ov;
  {
    const int j = tid;
    float a = LD<BF>(p.pool_out_b, j);
    for (int k = 0; k < NE; k += 4) {
      const float4 yy = *(const float4*)&sm.RowA[k];
      a += yy.x * LD<BF>(p.pool_out_w, (k + 0) * NP + j) +
           yy.y * LD<BF>(p.pool_out_w, (k + 1) * NP + j) +
           yy.z * LD<BF>(p.pool_out_w, (k + 2) * NP + j) +
           yy.w * LD<BF>(p.pool_out_w, (k + 3) * NP + j);
    }
    ov = a;
  }
  {
    const float s1 = block_sum(ov, sm.Red);
    const float s2 = block_sum(ov * ov, sm.Red);
    const float mu = s1 * (1.0f / NP);
    const float r  = rsqrtf(s2 * (1.0f / NP) - mu * mu + 1e-5f);
    const float res = (ov - mu) * r * LD<BF>(p.last_s, tid) + LD<BF>(p.last_b, tid);
    p.out[(size_t)s * NP + tid] = res;
  }
}

__global__ __launch_bounds__(NT, 1)   // r7-proven: 256 threads -> 136 VGPRs
void st_encoder_ws(Params p) {
  __shared__ Smem sm;
  const bool isbf = (((const u16*)p.ln1_s)[0] == 0x3F80);
  if (isbf) body<true, true>(p, sm);
  else      body<false, true>(p, sm);
}

__global__ __launch_bounds__(NT, 1)
void st_encoder_nows(Params p) {
  __shared__ Smem sm;
  const bool isbf = (((const u16*)p.ln1_s)[0] == 0x3F80);
  if (isbf) body<true, false>(p, sm);
  else      body<false, false>(p, sm);
}

extern "C" void kernel_launch(void* const* d_in, const int* in_sizes, int n_in,
                              void* d_out, int out_size, void* d_ws, size_t ws_size,
                              hipStream_t stream) {
  (void)in_sizes; (void)n_in; (void)out_size;
  Params p;
  p.x           = d_in[0];
  p.mask        = d_in[1];
  p.kp_w        = d_in[2];
  p.kp_b        = d_in[3];
  p.view_tokens = d_in[4];
  p.view_pos    = d_in[5];
  p.ln1_s       = d_in[6];
  p.ln1_b       = d_in[7];
  p.qkv_w       = d_in[8];
  p.qkv_b       = d_in[9];
  p.ap_w        = d_in[10];
  p.ap_b        = d_in[11];
  p.ln2_s       = d_in[12];
  p.ln2_b       = d_in[13];
  p.fc1_w       = d_in[14];
  p.fc1_b       = d_in[15];
  p.fc2_w       = d_in[16];
  p.fc2_b       = d_in[17];
  p.pool_probe  = d_in[18];
  p.pool_ln1_s  = d_in[19];
  p.pool_ln1_b  = d_in[20];
  p.pool_q_w    = d_in[21];
  p.pool_q_b    = d_in[22];
  p.pool_kv_w   = d_in[23];
  p.pool_kv_b   = d_in[24];
  p.pool_ap_w   = d_in[25];
  p.pool_ap_b   = d_in[26];
  p.pool_ln2_s  = d_in[27];
  p.pool_ln2_b  = d_in[28];
  p.pool_fc1_w  = d_in[29];
  p.pool_fc1_b  = d_in[30];
  p.pool_fc2_w  = d_in[31];
  p.pool_fc2_b  = d_in[32];
  p.pool_out_w  = d_in[33];
  p.pool_out_b  = d_in[34];
  p.last_s      = d_in[35];
  p.last_b      = d_in[36];
  p.out         = (float*)d_out;
  p.ws          = (u16*)d_ws;
  if (d_ws != nullptr && ws_size >= WS_NEEDED) {
    prep_kernel<<<dim3(WTOT / 256), dim3(256), 0, stream>>>(p);
    st_encoder_ws<<<dim3(NS), dim3(NT), 0, stream>>>(p);
  } else {
    st_encoder_nows<<<dim3(NS), dim3(NT), 0, stream>>>(p);
  }
}

// Round 14
// 8528.889 us; speedup vs baseline: 1.8844x; 1.8844x over previous
//
#include <hip/hip_runtime.h>
#include <hip/hip_bf16.h>
#include <math.h>

// ---------------------------------------------------------------------------
// SpatialTransformerEncoder — round 14: LDS diet -> 2 blocks/CU (8 waves).
// r13 fixed the spill (144 VGPRs, 256 threads) but 142 KB LDS gave 1 block/CU
// = 4 waves -> latency-bound (MfmaUtil 7%, VALU 6%, occ 12%). Cuts:
//  * A/H MFMA operand buffers 32->17 rows (row-16 fragment zero-masked)
//  * QKV/pool-KV outputs: Q,K bf16 (softmax-protected), V fp32
//  * FC-hidden + pool buffers overlay the attention QK/V region
// Total ~74 KB -> 2 blocks/CU. Skeleton/math otherwise identical to r13.
// ---------------------------------------------------------------------------

#define NB   2048
#define NC   3
#define NN   32
#define NE   256
#define NH   8
#define HDIM 32
#define NL   3
#define NMLP 1024
#define NP   256
#define NK   17
#define NS   (NB*NC)
#define NT   256       // threads per block (4 waves)
#define NW   4         // waves per block
#define AST  264

// ws layout (u16 offsets): hi block then lo block; [qkv][ap][fc1][fc2][kv],
// each [l][n][k] k-fastest (K=256 except fc2 K=1024).
#define SZ_QKV  589824
#define SZ_AP   196608
#define SZ_FC1  786432
#define SZ_FC2  786432
#define SZ_KV   131072
#define OFF_QKV 0
#define OFF_AP  (OFF_QKV + SZ_QKV)
#define OFF_FC1 (OFF_AP + SZ_AP)
#define OFF_FC2 (OFF_FC1 + SZ_FC1)
#define OFF_KV  (OFF_FC2 + SZ_FC2)
#define WTOT    (OFF_KV + SZ_KV)            // 2490368 u16 per polarity
#define WS_NEEDED ((size_t)WTOT * 2 * 2)

typedef unsigned short u16;
typedef __attribute__((ext_vector_type(8))) short short8;
typedef __attribute__((ext_vector_type(4))) float float4v;

struct Params {
  const void* x; const void* mask;
  const void* kp_w; const void* kp_b;
  const void* view_tokens; const void* view_pos;
  const void* ln1_s; const void* ln1_b;
  const void* qkv_w; const void* qkv_b;
  const void* ap_w; const void* ap_b;
  const void* ln2_s; const void* ln2_b;
  const void* fc1_w; const void* fc1_b;
  const void* fc2_w; const void* fc2_b;
  const void* pool_probe;
  const void* pool_ln1_s; const void* pool_ln1_b;
  const void* pool_q_w; const void* pool_q_b;
  const void* pool_kv_w; const void* pool_kv_b;
  const void* pool_ap_w; const void* pool_ap_b;
  const void* pool_ln2_s; const void* pool_ln2_b;
  const void* pool_fc1_w; const void* pool_fc1_b;
  const void* pool_fc2_w; const void* pool_fc2_b;
  const void* pool_out_w; const void* pool_out_b;
  const void* last_s; const void* last_b;
  float* out;
  u16* ws;
};

__device__ __forceinline__ float b2f(u16 u) {
  return __uint_as_float(((unsigned)u) << 16);
}
__device__ __forceinline__ u16 cvt16(float v) {
  return __bfloat16_as_ushort(__float2bfloat16(v));
}
__device__ __forceinline__ float geluf(float v) {
  return 0.5f * v * (1.0f + erff(v * 0.70710678118654752f));
}
template <bool BF>
__device__ __forceinline__ float LD(const void* q, int i) {
  if constexpr (BF) return b2f(((const u16*)q)[i]);
  else return ((const float*)q)[i];
}
__device__ __forceinline__ float4v vzero() {
  float4v z; z[0] = 0.f; z[1] = 0.f; z[2] = 0.f; z[3] = 0.f; return z;
}

// ---------------- prep: W[k][n] (fp32/bf16) -> ws hi/lo [n][k] ----------------
template <bool BF>
__device__ void prep_body(const Params& p, int idx) {
  size_t i = idx, src; const void* W;
  if (i < SZ_QKV) {
    const size_t l = i / 196608, r = i % 196608, n = r / 256, k = r % 256;
    W = p.qkv_w; src = l * 196608 + k * 768 + n;
  } else if ((i -= SZ_QKV) < SZ_AP) {
    const size_t l = i / 65536, r = i % 65536, n = r / 256, k = r % 256;
    W = p.ap_w; src = l * 65536 + k * 256 + n;
  } else if ((i -= SZ_AP) < SZ_FC1) {
    const size_t l = i / 262144, r = i % 262144, n = r / 256, k = r % 256;
    W = p.fc1_w; src = l * 262144 + k * 1024 + n;
  } else if ((i -= SZ_FC1) < SZ_FC2) {
    const size_t l = i / 262144, r = i % 262144, n = r / 1024, k = r % 1024;
    W = p.fc2_w; src = l * 262144 + k * 256 + n;
  } else {
    i -= SZ_FC2;
    const size_t n = i / 256, k = i % 256;
    W = p.pool_kv_w; src = k * 512 + n;
  }
  u16 hi, lo;
  if constexpr (BF) {
    hi = ((const u16*)W)[src]; lo = 0;
  } else {
    const float wv = ((const float*)W)[src];
    hi = cvt16(wv);
    lo = cvt16(wv - b2f(hi));
  }
  p.ws[idx] = hi;
  p.ws[WTOT + idx] = lo;
}

__global__ __launch_bounds__(256)
void prep_kernel(Params p) {
  const int idx = blockIdx.x * 256 + threadIdx.x;
  if (idx >= WTOT) return;
  const bool isbf = (((const u16*)p.ln1_s)[0] == 0x3F80);
  if (isbf) prep_body<true>(p, idx);
  else      prep_body<false>(p, idx);
}

// ---------------- shared memory (~74 KB) ----------------
struct alignas(16) Smem {
  float X[NK][NE];        // 17408  residual stream
  u16  Ahi[NK * AST];     // 8976   MFMA A operand hi (17 rows)
  u16  Alo[NK * AST];     // 8976
  u16  Bh[NK * 512];      // 17408  attn: q,k bf16 | FC: Hhi (17*AST u16)
  float Bv[NK][NE];       // 17408  attn: v fp32   | FC: Hlo (u16*) | pool: Hh (float*)
  float Q[NE];            // 1024   pool q / normalized-y row
  float O[NE];            // 1024
  float RowA[NE];         // 1024
  float Pp[NH][NK];       // 544
  float Red[NW];          // 16
  int  Idx[NK];           // 68
};

// ---- LayerNorm over 17 rows -> hi/lo bf16 A-buffers (4 waves) ----
template <bool BF>
__device__ __forceinline__ void ln_hl(const float* __restrict__ In,
                                      u16* __restrict__ Oh, u16* __restrict__ Ol,
                                      const void* __restrict__ gam,
                                      const void* __restrict__ bet) {
  const int lane = threadIdx.x & 63, w = threadIdx.x >> 6;
  for (int t = w; t < NK; t += NW) {
    const float* row = In + t * NE;
    float sum = 0.f, sq = 0.f;
#pragma unroll
    for (int kk = 0; kk < NE / 64; ++kk) {
      const float v = row[lane + 64 * kk];
      sum += v; sq += v * v;
    }
#pragma unroll
    for (int off = 32; off > 0; off >>= 1) {
      sum += __shfl_down(sum, off, 64);
      sq  += __shfl_down(sq,  off, 64);
    }
    sum = __shfl(sum, 0, 64);
    sq  = __shfl(sq,  0, 64);
    const float mu = sum * (1.0f / NE);
    const float r  = rsqrtf(sq * (1.0f / NE) - mu * mu + 1e-5f);
#pragma unroll
    for (int kk = 0; kk < NE / 64; ++kk) {
      const int k = lane + 64 * kk;
      const float v = (row[k] - mu) * r * LD<BF>(gam, k) + LD<BF>(bet, k);
      const u16 hv = cvt16(v);
      Oh[t * AST + k] = hv;
      Ol[t * AST + k] = cvt16(v - b2f(hv));
    }
  }
}

// ---- MFMA tile (WS): A has 17 rows; row-16 fragment zero-masked (col!=0) ----
template <bool BF>
__device__ __forceinline__ void mfma_ws(const u16* __restrict__ Ah,
                                        const u16* __restrict__ Al,
                                        const u16* __restrict__ Wh,
                                        const u16* __restrict__ Wl,
                                        const int kst, const int koff,
                                        const int n,
                                        float4v& D0, float4v& D1) {
  const int lane = threadIdx.x & 63;
  const int col = lane & 15, quad = lane >> 4;
  const u16* __restrict__ brh = Wh + (size_t)n * kst + koff;
  const u16* __restrict__ brl = Wl + (size_t)n * kst + koff;
  const short8 z8 = {0, 0, 0, 0, 0, 0, 0, 0};
  for (int ks = 0; ks < 8; ++ks) {
    const int k0 = ks * 32 + quad * 8;
    const short8 ah0 = *(const short8*)(Ah + col * AST + k0);
    short8 ah1 = z8, al1 = z8;
    if (col == 0) {
      ah1 = *(const short8*)(Ah + 16 * AST + k0);
      al1 = *(const short8*)(Al + 16 * AST + k0);
    }
    const short8 bh = *(const short8*)(brh + k0);
    D0 = __builtin_amdgcn_mfma_f32_16x16x32_bf16(ah0, bh, D0, 0, 0, 0);
    D1 = __builtin_amdgcn_mfma_f32_16x16x32_bf16(ah1, bh, D1, 0, 0, 0);
    {
      const short8 al0 = *(const short8*)(Al + col * AST + k0);
      D0 = __builtin_amdgcn_mfma_f32_16x16x32_bf16(al0, bh, D0, 0, 0, 0);
      D1 = __builtin_amdgcn_mfma_f32_16x16x32_bf16(al1, bh, D1, 0, 0, 0);
    }
    if constexpr (!BF) {
      const short8 bl = *(const short8*)(brl + k0);
      D0 = __builtin_amdgcn_mfma_f32_16x16x32_bf16(ah0, bl, D0, 0, 0, 0);
      D1 = __builtin_amdgcn_mfma_f32_16x16x32_bf16(ah1, bl, D1, 0, 0, 0);
    }
  }
}

// ---- MFMA tile, inline fallback (W fp32/bf16 row-major global) ----
template <bool BF>
__device__ __forceinline__ void mfma_in(const u16* __restrict__ Ah,
                                        const u16* __restrict__ Al,
                                        const void* __restrict__ W, const int wN,
                                        const int n,
                                        float4v& D0, float4v& D1) {
  const int lane = threadIdx.x & 63;
  const int col = lane & 15, quad = lane >> 4;
  const short8 z8 = {0, 0, 0, 0, 0, 0, 0, 0};
  for (int ks = 0; ks < 8; ++ks) {
    const int k0 = ks * 32 + quad * 8;
    const short8 ah0 = *(const short8*)(Ah + col * AST + k0);
    short8 ah1 = z8, al1 = z8;
    if (col == 0) {
      ah1 = *(const short8*)(Ah + 16 * AST + k0);
      al1 = *(const short8*)(Al + 16 * AST + k0);
    }
    short8 bh, bl;
#pragma unroll
    for (int j2 = 0; j2 < 8; ++j2) {
      const size_t off = (size_t)(k0 + j2) * wN + n;
      if constexpr (BF) {
        bh[j2] = (short)((const u16*)W)[off];
      } else {
        const float wv = ((const float*)W)[off];
        const u16 hv = cvt16(wv);
        bh[j2] = (short)hv;
        bl[j2] = (short)cvt16(wv - b2f(hv));
      }
    }
    D0 = __builtin_amdgcn_mfma_f32_16x16x32_bf16(ah0, bh, D0, 0, 0, 0);
    D1 = __builtin_amdgcn_mfma_f32_16x16x32_bf16(ah1, bh, D1, 0, 0, 0);
    {
      const short8 al0 = *(const short8*)(Al + col * AST + k0);
      D0 = __builtin_amdgcn_mfma_f32_16x16x32_bf16(al0, bh, D0, 0, 0, 0);
      D1 = __builtin_amdgcn_mfma_f32_16x16x32_bf16(al1, bh, D1, 0, 0, 0);
    }
    if constexpr (!BF) {
      D0 = __builtin_amdgcn_mfma_f32_16x16x32_bf16(ah0, bl, D0, 0, 0, 0);
      D1 = __builtin_amdgcn_mfma_f32_16x16x32_bf16(ah1, bl, D1, 0, 0, 0);
    }
  }
}

__device__ __forceinline__ float block_sum(float v, float* sRed) {
#pragma unroll
  for (int off = 32; off > 0; off >>= 1) v += __shfl_down(v, off, 64);
  __syncthreads();
  if ((threadIdx.x & 63) == 0) sRed[threadIdx.x >> 6] = v;
  __syncthreads();
  return sRed[0] + sRed[1] + sRed[2] + sRed[3];
}

template <bool BF, bool WS>
__device__ void body(const Params& p, Smem& sm) {
  const int s   = blockIdx.x;
  const int c   = s % NC;
  const int tid = threadIdx.x;
  const size_t EB = BF ? 2 : 4;
  const int lane = tid & 63, wv_ = tid >> 6, col = lane & 15, quad = lane >> 4;
  const u16* wsh = p.ws;
  const u16* wsl = p.ws + WTOT;
  u16* Hhi = sm.Bh;                  // FC hidden hi (17*AST u16 <= 17*512)
  u16* Hlo = (u16*)&sm.Bv[0][0];     // FC hidden lo (aliases attn-V region)

  if (tid == 0) {
    const unsigned int* mw = (const unsigned int*)p.mask;
    bool byte_layout = false;
    for (int i = 0; i < 8; ++i) {
      const unsigned int w = mw[i];
      if (w != 0u && w != 1u && w != 0x3F800000u) { byte_layout = true; break; }
    }
    int np_ = 0;
    sm.Idx[np_++] = -1;
    if (byte_layout) {
      const unsigned char* mb = (const unsigned char*)p.mask;
      for (int n = 0; n < NN && np_ < NK; ++n)
        if (mb[(size_t)s * NN + n]) sm.Idx[np_++] = n;
    } else {
      for (int n = 0; n < NN && np_ < NK; ++n)
        if (mw[(size_t)s * NN + n] != 0u) sm.Idx[np_++] = n;
    }
    while (np_ < NK) sm.Idx[np_++] = 0;
  }
  __syncthreads();

  // embedding
  {
    const int e = tid;
    const float kw0 = LD<BF>(p.kp_w, e);
    const float kw1 = LD<BF>(p.kp_w, NE + e);
    const float kb  = LD<BF>(p.kp_b, e);
    const int   i2  = e & ~1;
    const float freq = expf(-((float)i2 / (float)NE) * logf(10000.0f));
    const float vt = LD<BF>(p.view_tokens, c * NE + e) + LD<BF>(p.view_pos, c * NE + e);
    for (int t = 0; t < NK; ++t) {
      const int n = sm.Idx[t];
      float v;
      if (n < 0) {
        v = vt;
      } else {
        const float x0 = LD<BF>(p.x, (s * NN + n) * 2 + 0);
        const float x1 = LD<BF>(p.x, (s * NN + n) * 2 + 1);
        const float ang = (float)n * freq;
        const float pe  = (e & 1) ? cosf(ang) : sinf(ang);
        v = x0 * kw0 + x1 * kw1 + kb + pe;
      }
      sm.X[t][e] = v;
    }
  }
  __syncthreads();

  for (int l = 0; l < NL; ++l) {
    const void* qkvw = (const char*)p.qkv_w + (size_t)l * NE * 3 * NE * EB;
    const void* qkvb = (const char*)p.qkv_b + (size_t)l * 3 * NE * EB;
    const void* apw  = (const char*)p.ap_w  + (size_t)l * NE * NE * EB;
    const void* apb  = (const char*)p.ap_b  + (size_t)l * NE * EB;
    const void* f1b  = (const char*)p.fc1_b + (size_t)l * NMLP * EB;
    const void* f2bb = (const char*)p.fc2_b + (size_t)l * NE * EB;

    ln_hl<BF>(&sm.X[0][0], sm.Ahi, sm.Alo,
              (const char*)p.ln1_s + (size_t)l * NE * EB,
              (const char*)p.ln1_b + (size_t)l * NE * EB);
    __syncthreads();

    // QKV: 48 N-tiles, 12 per wave. n<512 -> q,k bf16 into Bh; else v fp32 Bv.
    for (int jj = 0; jj < 12; ++jj) {
      const int n = (wv_ + jj * NW) * 16 + col;
      float4v D0 = vzero(), D1 = vzero();
      if constexpr (WS)
        mfma_ws<BF>(sm.Ahi, sm.Alo, wsh + OFF_QKV + (size_t)l * 196608,
                    wsl + OFF_QKV + (size_t)l * 196608, 256, 0, n, D0, D1);
      else
        mfma_in<BF>(sm.Ahi, sm.Alo, qkvw, 3 * NE, n, D0, D1);
      const float bb = LD<BF>(qkvb, n);
#pragma unroll
      for (int r = 0; r < 4; ++r) {
        const int m0 = quad * 4 + r;
        const int m1 = 16 + quad * 4 + r;
        if (n < 512) {
          if (m0 < NK) sm.Bh[m0 * 512 + n] = cvt16(D0[r] + bb);
          if (m1 < NK) sm.Bh[m1 * 512 + n] = cvt16(D1[r] + bb);
        } else {
          if (m0 < NK) sm.Bv[m0][n - 512] = D0[r] + bb;
          if (m1 < NK) sm.Bv[m1][n - 512] = D1[r] + bb;
        }
      }
    }
    __syncthreads();

    // attention (VALU): q,k bf16 from Bh; v fp32 from Bv; context -> A hi/lo
    if (tid < NH * NK) {
      const int h = tid / NK, t = tid % NK;
      float sc[NK];
      float mx = -1e30f;
#pragma unroll
      for (int u = 0; u < NK; ++u) {
        float d = 0.f;
        for (int i = 0; i < HDIM; ++i)
          d += b2f(sm.Bh[t * 512 + h * HDIM + i]) *
               b2f(sm.Bh[u * 512 + 256 + h * HDIM + i]);
        d *= 0.17677669529663687f;
        sc[u] = d;
        mx = fmaxf(mx, d);
      }
      float den = 0.f;
#pragma unroll
      for (int u = 0; u < NK; ++u) { sc[u] = __expf(sc[u] - mx); den += sc[u]; }
      const float inv = 1.0f / den;
      for (int i = 0; i < HDIM; ++i) {
        float o = 0.f;
#pragma unroll
        for (int u = 0; u < NK; ++u) o += sc[u] * sm.Bv[u][h * HDIM + i];
        o *= inv;
        const int jc = h * HDIM + i;
        const u16 hv = cvt16(o);
        sm.Ahi[t * AST + jc] = hv;
        sm.Alo[t * AST + jc] = cvt16(o - b2f(hv));
      }
    }
    __syncthreads();

    // proj + residual: 16 tiles, 4 per wave
    for (int jj = 0; jj < 4; ++jj) {
      const int n = (wv_ + jj * NW) * 16 + col;
      float4v D0 = vzero(), D1 = vzero();
      if constexpr (WS)
        mfma_ws<BF>(sm.Ahi, sm.Alo, wsh + OFF_AP + (size_t)l * 65536,
                    wsl + OFF_AP + (size_t)l * 65536, 256, 0, n, D0, D1);
      else
        mfma_in<BF>(sm.Ahi, sm.Alo, apw, NE, n, D0, D1);
      const float bb = LD<BF>(apb, n);
#pragma unroll
      for (int r = 0; r < 4; ++r) {
        const int m0 = quad * 4 + r;
        if (m0 < NK) sm.X[m0][n] = sm.X[m0][n] + D0[r] + bb;
        const int m1 = 16 + quad * 4 + r;
        if (m1 < NK) sm.X[m1][n] = sm.X[m1][n] + D1[r] + bb;
      }
    }
    __syncthreads();

    ln_hl<BF>(&sm.X[0][0], sm.Ahi, sm.Alo,
              (const char*)p.ln2_s + (size_t)l * NE * EB,
              (const char*)p.ln2_b + (size_t)l * NE * EB);
    __syncthreads();

    // FC1 (+GELU) chunk -> H (hi in Bh, lo in Bv); FC2 chunk partial -> X
    for (int chunk = 0; chunk < 4; ++chunk) {
      for (int jj = 0; jj < 4; ++jj) {
        const int n = (wv_ + jj * NW) * 16 + col;
        float4v D0 = vzero(), D1 = vzero();
        if constexpr (WS)
          mfma_ws<BF>(sm.Ahi, sm.Alo,
                      wsh + OFF_FC1 + (size_t)l * 262144 + (size_t)chunk * 65536,
                      wsl + OFF_FC1 + (size_t)l * 262144 + (size_t)chunk * 65536,
                      256, 0, n, D0, D1);
        else {
          const void* f1w = (const char*)p.fc1_w +
              ((size_t)l * NE * NMLP + (size_t)chunk * 256) * EB;
          mfma_in<BF>(sm.Ahi, sm.Alo, f1w, NMLP, n, D0, D1);
        }
        const float bb = LD<BF>(f1b, chunk * 256 + n);
#pragma unroll
        for (int r = 0; r < 4; ++r) {
          const int m0 = quad * 4 + r;
          if (m0 < NK) {
            const float v = geluf(D0[r] + bb);
            const u16 hv = cvt16(v);
            Hhi[m0 * AST + n] = hv;
            Hlo[m0 * AST + n] = cvt16(v - b2f(hv));
          }
          const int m1 = 16 + quad * 4 + r;
          if (m1 < NK) {
            const float v = geluf(D1[r] + bb);
            const u16 hv = cvt16(v);
            Hhi[m1 * AST + n] = hv;
            Hlo[m1 * AST + n] = cvt16(v - b2f(hv));
          }
        }
      }
      __syncthreads();
      for (int jj = 0; jj < 4; ++jj) {
        const int n = (wv_ + jj * NW) * 16 + col;
        float4v D0 = vzero(), D1 = vzero();
        if constexpr (WS)
          mfma_ws<BF>(Hhi, Hlo, wsh + OFF_FC2 + (size_t)l * 262144,
                      wsl + OFF_FC2 + (size_t)l * 262144,
                      1024, chunk * 256, n, D0, D1);
        else {
          const void* f2w = (const char*)p.fc2_w +
              ((size_t)l * NMLP * NE + (size_t)chunk * 256 * NE) * EB;
          mfma_in<BF>(Hhi, Hlo, f2w, NE, n, D0, D1);
        }
        const float bb = (chunk == 0) ? LD<BF>(f2bb, n) : 0.f;
#pragma unroll
        for (int r = 0; r < 4; ++r) {
          const int m0 = quad * 4 + r;
          if (m0 < NK) sm.X[m0][n] = sm.X[m0][n] + D0[r] + bb;
          const int m1 = 16 + quad * 4 + r;
          if (m1 < NK) sm.X[m1][n] = sm.X[m1][n] + D1[r] + bb;
        }
      }
      __syncthreads();
    }
  }

  // ---- attention pooling ----
  ln_hl<BF>(&sm.X[0][0], sm.Ahi, sm.Alo, p.pool_ln1_s, p.pool_ln1_b);
  __syncthreads();
  {
    const int j = tid;
    float a = LD<BF>(p.pool_q_b, j);
    for (int k = 0; k < NE; k += 4) {
      a += LD<BF>(p.pool_probe, k + 0) * LD<BF>(p.pool_q_w, (k + 0) * NE + j) +
           LD<BF>(p.pool_probe, k + 1) * LD<BF>(p.pool_q_w, (k + 1) * NE + j) +
           LD<BF>(p.pool_probe, k + 2) * LD<BF>(p.pool_q_w, (k + 2) * NE + j) +
           LD<BF>(p.pool_probe, k + 3) * LD<BF>(p.pool_q_w, (k + 3) * NE + j);
    }
    sm.Q[j] = a;
  }
  // pool KV: 32 tiles, 8 per wave. n<256 -> kk bf16 Bh; else vv fp32 Bv.
  for (int jj = 0; jj < 8; ++jj) {
    const int n = (wv_ + jj * NW) * 16 + col;
    float4v D0 = vzero(), D1 = vzero();
    if constexpr (WS)
      mfma_ws<BF>(sm.Ahi, sm.Alo, wsh + OFF_KV, wsl + OFF_KV, 256, 0, n, D0, D1);
    else
      mfma_in<BF>(sm.Ahi, sm.Alo, p.pool_kv_w, 2 * NE, n, D0, D1);
    const float bb = LD<BF>(p.pool_kv_b, n);
#pragma unroll
    for (int r = 0; r < 4; ++r) {
      const int m0 = quad * 4 + r;
      const int m1 = 16 + quad * 4 + r;
      if (n < 256) {
        if (m0 < NK) sm.Bh[m0 * 512 + n] = cvt16(D0[r] + bb);
        if (m1 < NK) sm.Bh[m1 * 512 + n] = cvt16(D1[r] + bb);
      } else {
        if (m0 < NK) sm.Bv[m0][n - 256] = D0[r] + bb;
        if (m1 < NK) sm.Bv[m1][n - 256] = D1[r] + bb;
      }
    }
  }
  __syncthreads();
  if (tid < NH) {
    const int h = tid;
    float sc[NK];
    float mx = -1e30f;
#pragma unroll
    for (int u = 0; u < NK; ++u) {
      float d = 0.f;
      for (int i = 0; i < HDIM; ++i)
        d += sm.Q[h * HDIM + i] * b2f(sm.Bh[u * 512 + h * HDIM + i]);
      d *= 0.17677669529663687f;
      sc[u] = d;
      mx = fmaxf(mx, d);
    }
    float den = 0.f;
#pragma unroll
    for (int u = 0; u < NK; ++u) { sc[u] = __expf(sc[u] - mx); den += sc[u]; }
    const float inv = 1.0f / den;
#pragma unroll
    for (int u = 0; u < NK; ++u) sm.Pp[h][u] = sc[u] * inv;
  }
  __syncthreads();
  {
    const int j = tid, h = j >> 5, i = j & 31;
    float o = 0.f;
#pragma unroll
    for (int u = 0; u < NK; ++u) o += sm.Pp[h][u] * sm.Bv[u][h * HDIM + i];
    sm.O[j] = o;
  }
  __syncthreads();
  float yv;
  {
    const int j = tid;
    float a = LD<BF>(p.pool_ap_b, j);
    for (int k = 0; k < NE; k += 4) {
      const float4 oo = *(const float4*)&sm.O[k];
      a += oo.x * LD<BF>(p.pool_ap_w, (k + 0) * NE + j) +
           oo.y * LD<BF>(p.pool_ap_w, (k + 1) * NE + j) +
           oo.z * LD<BF>(p.pool_ap_w, (k + 2) * NE + j) +
           oo.w * LD<BF>(p.pool_ap_w, (k + 3) * NE + j);
    }
    yv = LD<BF>(p.pool_probe, j) + a;
  }
  {
    const float s1 = block_sum(yv, sm.Red);
    const float s2 = block_sum(yv * yv, sm.Red);
    const float mu = s1 * (1.0f / NE);
    const float r  = rsqrtf(s2 * (1.0f / NE) - mu * mu + 1e-5f);
    sm.Q[tid] = (yv - mu) * r * LD<BF>(p.pool_ln2_s, tid) + LD<BF>(p.pool_ln2_b, tid);
  }
  __syncthreads();
  // pool MLP hidden: 4 cols per thread -> Hh aliases Bv (attn V dead)
  float* Hh = (float*)&sm.Bv[0][0];
  {
    const int j = tid;
    float h1[4];
#pragma unroll
    for (int c4 = 0; c4 < 4; ++c4) h1[c4] = LD<BF>(p.pool_fc1_b, c4 * NE + j);
    for (int k = 0; k < NE; k += 4) {
      const float4 nq = *(const float4*)&sm.Q[k];
#pragma unroll
      for (int c4 = 0; c4 < 4; ++c4) {
        const int cjj = c4 * NE + j;
        h1[c4] += nq.x * LD<BF>(p.pool_fc1_w, (k + 0) * NMLP + cjj) +
                  nq.y * LD<BF>(p.pool_fc1_w, (k + 1) * NMLP + cjj) +
                  nq.z * LD<BF>(p.pool_fc1_w, (k + 2) * NMLP + cjj) +
                  nq.w * LD<BF>(p.pool_fc1_w, (k + 3) * NMLP + cjj);
      }
    }
    __syncthreads();   // ensure all Bv (attn V) reads done before overwrite
#pragma unroll
    for (int c4 = 0; c4 < 4; ++c4) Hh[c4 * NE + j] = geluf(h1[c4]);
  }
  __syncthreads();
  {
    const int j = tid;
    float a = LD<BF>(p.pool_fc2_b, j);
    for (int k = 0; k < NMLP; k += 4) {
      const float4 hh = *(const float4*)&Hh[k];
      a += hh.x * LD<BF>(p.pool_fc2_w, (k + 0) * NE + j) +
           hh.y * LD<BF>(p.pool_fc2_w, (k + 1) * NE + j) +
           hh.z * LD<BF>(p.pool_fc2_w, (k + 2) * NE + j) +
           hh.w * LD<BF>(p.pool_fc2_w, (k + 3) * NE + j);
    }
    yv += a;
    sm.RowA[j] = yv;
  }
  __syncthreads();
  float ov;
  {
    const int j = tid;
    float a = LD<BF>(p.pool_out_b, j);
    for (int k = 0; k < NE; k += 4) {
      const float4 yy = *(const float4*)&sm.RowA[k];
      a += yy.x * LD<BF>(p.pool_out_w, (k + 0) * NP + j) +
           yy.y * LD<BF>(p.pool_out_w, (k + 1) * NP + j) +
           yy.z * LD<BF>(p.pool_out_w, (k + 2) * NP + j) +
           yy.w * LD<BF>(p.pool_out_w, (k + 3) * NP + j);
    }
    ov = a;
  }
  {
    const float s1 = block_sum(ov, sm.Red);
    const float s2 = block_sum(ov * ov, sm.Red);
    const float mu = s1 * (1.0f / NP);
    const float r  = rsqrtf(s2 * (1.0f / NP) - mu * mu + 1e-5f);
    const float res = (ov - mu) * r * LD<BF>(p.last_s, tid) + LD<BF>(p.last_b, tid);
    p.out[(size_t)s * NP + tid] = res;
  }
}

__global__ __launch_bounds__(NT, 2)   // 2 blocks/CU (8 waves) via ~74 KB LDS
void st_encoder_ws(Params p) {
  __shared__ Smem sm;
  const bool isbf = (((const u16*)p.ln1_s)[0] == 0x3F80);
  if (isbf) body<true, true>(p, sm);
  else      body<false, true>(p, sm);
}

__global__ __launch_bounds__(NT, 2)
void st_encoder_nows(Params p) {
  __shared__ Smem sm;
  const bool isbf = (((const u16*)p.ln1_s)[0] == 0x3F80);
  if (isbf) body<true, false>(p, sm);
  else      body<false, false>(p, sm);
}

extern "C" void kernel_launch(void* const* d_in, const int* in_sizes, int n_in,
                              void* d_out, int out_size, void* d_ws, size_t ws_size,
                              hipStream_t stream) {
  (void)in_sizes; (void)n_in; (void)out_size;
  Params p;
  p.x           = d_in[0];
  p.mask        = d_in[1];
  p.kp_w        = d_in[2];
  p.kp_b        = d_in[3];
  p.view_tokens = d_in[4];
  p.view_pos    = d_in[5];
  p.ln1_s       = d_in[6];
  p.ln1_b       = d_in[7];
  p.qkv_w       = d_in[8];
  p.qkv_b       = d_in[9];
  p.ap_w        = d_in[10];
  p.ap_b        = d_in[11];
  p.ln2_s       = d_in[12];
  p.ln2_b       = d_in[13];
  p.fc1_w       = d_in[14];
  p.fc1_b       = d_in[15];
  p.fc2_w       = d_in[16];
  p.fc2_b       = d_in[17];
  p.pool_probe  = d_in[18];
  p.pool_ln1_s  = d_in[19];
  p.pool_ln1_b  = d_in[20];
  p.pool_q_w    = d_in[21];
  p.pool_q_b    = d_in[22];
  p.pool_kv_w   = d_in[23];
  p.pool_kv_b   = d_in[24];
  p.pool_ap_w   = d_in[25];
  p.pool_ap_b   = d_in[26];
  p.pool_ln2_s  = d_in[27];
  p.pool_ln2_b  = d_in[28];
  p.pool_fc1_w  = d_in[29];
  p.pool_fc1_b  = d_in[30];
  p.pool_fc2_w  = d_in[31];
  p.pool_fc2_b  = d_in[32];
  p.pool_out_w  = d_in[33];
  p.pool_out_b  = d_in[34];
  p.last_s      = d_in[35];
  p.last_b      = d_in[36];
  p.out         = (float*)d_out;
  p.ws          = (u16*)d_ws;
  if (d_ws != nullptr && ws_size >= WS_NEEDED) {
    prep_kernel<<<dim3((WTOT + 255) / 256), dim3(256), 0, stream>>>(p);
    st_encoder_ws<<<dim3(NS), dim3(NT), 0, stream>>>(p);
  } else {
    st_encoder_nows<<<dim3(NS), dim3(NT), 0, stream>>>(p);
  }
}